// Round 6
// baseline (422.869 us; speedup 1.0000x reference)
//
#include <hip/hip_runtime.h>
#include <math.h>

#define B_    32
#define L_    4096
#define N_    256
#define NC    2048            // complex FFT length (real-packed)
#define NSEG  32
#define SEGLEN (L_ / NSEG)    // 128
#define CHUNK 32
#define NCH   (SEGLEN / CHUNK) // 4
#define NQ    9               // S1,S2,S3,S4,C1,C3,C6,C12,C24
#define NCAND 8               // fp32 candidates kept for fp64 re-rank

__device__ __forceinline__ int PD(int i) { return i + (i >> 3); }  // pad every 8 elems

// ---------------- fused stats partials + transpose ----------------
// P[((s*B + b)*NQ + q)*N + n]; xt (B,N,L) written when do_t != 0
__global__ __launch_bounds__(256, 4) void k_stats_trans(const float* __restrict__ x,
                                                        float* __restrict__ P,
                                                        float* __restrict__ xt,
                                                        int do_t) {
  __shared__ float tile[CHUNK][N_ + 1];   // +1 pad: conflict-free transpose read
  const int s = blockIdx.x;
  const int b = blockIdx.y;
  const int n = threadIdx.x;
  const int l0 = s * SEGLEN;
  const float* xp = x + (size_t)b * L_ * N_ + n;
  float* xtb = xt + (size_t)b * N_ * L_;

  float prev[CHUNK];
#pragma unroll
  for (int j = 0; j < CHUNK; ++j) {
    const int l = l0 - CHUNK + j;
    prev[j] = (l >= 0) ? xp[(size_t)l * N_] : 0.0f;  // zero-fill: missing pairs add 0
  }
  float s1 = 0.f, s2 = 0.f, s3 = 0.f, s4 = 0.f;
  float c1 = 0.f, c3 = 0.f, c6 = 0.f, c12 = 0.f, c24 = 0.f;
  for (int c = 0; c < NCH; ++c) {
    const int lb = l0 + c * CHUNK;
    float cur[CHUNK];
#pragma unroll
    for (int j = 0; j < CHUNK; ++j) cur[j] = xp[(size_t)(lb + j) * N_];
#pragma unroll
    for (int j = 0; j < CHUNK; ++j) {
      const float v = cur[j], v2 = v * v;
      s1 += v; s2 += v2; s3 += v2 * v; s4 += v2 * v2;
    }
#pragma unroll
    for (int j = 0; j < CHUNK; ++j) {
      const float v = cur[j];
      c1  += v * ((j >= 1)  ? cur[j - 1]  : prev[CHUNK + j - 1]);
      c3  += v * ((j >= 3)  ? cur[j - 3]  : prev[CHUNK + j - 3]);
      c6  += v * ((j >= 6)  ? cur[j - 6]  : prev[CHUNK + j - 6]);
      c12 += v * ((j >= 12) ? cur[j - 12] : prev[CHUNK + j - 12]);
      c24 += v * ((j >= 24) ? cur[j - 24] : prev[CHUNK + j - 24]);
    }
    if (do_t) {
#pragma unroll
      for (int j = 0; j < CHUNK; ++j) tile[j][n] = cur[j];
      __syncthreads();
#pragma unroll
      for (int it = 0; it < 8; ++it) {
        const int g  = n + 256 * it;        // [0, 2048)
        const int np = g >> 3;              // column (n') index
        const int j4 = g & 7;               // float4 within the 32-float row
        float4 w;
        w.x = tile[4 * j4 + 0][np];
        w.y = tile[4 * j4 + 1][np];
        w.z = tile[4 * j4 + 2][np];
        w.w = tile[4 * j4 + 3][np];
        *(float4*)(xtb + (size_t)np * L_ + lb + 4 * j4) = w;
      }
      __syncthreads();
    }
#pragma unroll
    for (int j = 0; j < CHUNK; ++j) prev[j] = cur[j];
  }
  float* Pp = P + (size_t)(s * B_ + b) * NQ * N_ + n;
  Pp[0 * N_] = s1; Pp[1 * N_] = s2; Pp[2 * N_] = s3; Pp[3 * N_] = s4;
  Pp[4 * N_] = c1; Pp[5 * N_] = c3; Pp[6 * N_] = c6; Pp[7 * N_] = c12; Pp[8 * N_] = c24;
}

// ---------------- stats finalize: mean/std/skew/kurt + ac[5] ----------------
__global__ __launch_bounds__(256) void k_stats_final(const float* __restrict__ x,
                                                     const float* __restrict__ P,
                                                     float* __restrict__ out) {
  const int b = blockIdx.x;
  const int n = threadIdx.x;
  float S[NQ];
#pragma unroll
  for (int q = 0; q < NQ; ++q) S[q] = 0.0f;
  for (int s = 0; s < NSEG; ++s) {
    const float* Pp = P + (size_t)(s * B_ + b) * NQ * N_ + n;
#pragma unroll
    for (int q = 0; q < NQ; ++q) S[q] += Pp[q * N_];
  }
  const float Lf = (float)L_;
  const float mu = S[0] / Lf;
  float ssd = S[1] - Lf * mu * mu;
  ssd = fmaxf(ssd, 0.0f);
  const float stdv = sqrtf(ssd / (Lf - 1.0f));     // ddof=1
  const float se  = stdv + 1e-8f;
  const float m3 = (S[2] - 3.0f * mu * S[1] + 2.0f * Lf * mu * mu * mu) / Lf;
  const float m4 = (S[3] - 4.0f * mu * S[2] + 6.0f * mu * mu * S[1]
                    - 3.0f * Lf * mu * mu * mu * mu) / Lf;
  const float se2 = se * se;
  const float skew = m3 / (se2 * se + 1e-8f);
  const float kurt = m4 / (se2 * se2 + 1e-8f) - 3.0f;

  const float* xp = x + (size_t)b * L_ * N_ + n;
  float hl[5], tl[5];
  {
    float hs = 0.0f, ts = 0.0f;
#pragma unroll
    for (int t = 0; t < 24; ++t) {
      hs += xp[(size_t)t * N_];
      ts += xp[(size_t)(L_ - 1 - t) * N_];
      if (t == 0)  { hl[0] = hs; tl[0] = ts; }
      if (t == 2)  { hl[1] = hs; tl[1] = ts; }
      if (t == 5)  { hl[2] = hs; tl[2] = ts; }
      if (t == 11) { hl[3] = hs; tl[3] = ts; }
      if (t == 23) { hl[4] = hs; tl[4] = ts; }
    }
  }
  float* op = out + ((size_t)b * N_ + n) * 19;
  op[0] = mu; op[1] = stdv; op[2] = skew; op[3] = kurt;
  const int lags[5] = {1, 3, 6, 12, 24};
  const float inv_se2 = 1.0f / se2;
#pragma unroll
  for (int i = 0; i < 5; ++i) {
    const float cnt = (float)(L_ - lags[i]);
    const float SA = S[0] - tl[i];
    const float SB = S[0] - hl[i];
    const float num = S[4 + i] - mu * (SA + SB) + cnt * mu * mu;
    op[14 + i] = num * inv_se2 / cnt;
  }
}

// ---------------- 8-point DFT in registers (forward, w8 = e^{-i pi/4}) --------
__device__ __forceinline__ void dft8(float (&vr)[8], float (&vi)[8]) {
  const float C7 = 0.70710678118654752f;
  float t0r = vr[0] + vr[4], t0i = vi[0] + vi[4];
  float t1r = vr[0] - vr[4], t1i = vi[0] - vi[4];
  float t2r = vr[2] + vr[6], t2i = vi[2] + vi[6];
  float t3r = vr[2] - vr[6], t3i = vi[2] - vi[6];
  float E0r = t0r + t2r, E0i = t0i + t2i;
  float E2r = t0r - t2r, E2i = t0i - t2i;
  float E1r = t1r + t3i, E1i = t1i - t3r;
  float E3r = t1r - t3i, E3i = t1i + t3r;
  float u0r = vr[1] + vr[5], u0i = vi[1] + vi[5];
  float u1r = vr[1] - vr[5], u1i = vi[1] - vi[5];
  float u2r = vr[3] + vr[7], u2i = vi[3] + vi[7];
  float u3r = vr[3] - vr[7], u3i = vi[3] - vi[7];
  float O0r = u0r + u2r, O0i = u0i + u2i;
  float O2r = u0r - u2r, O2i = u0i - u2i;
  float O1r = u1r + u3i, O1i = u1i - u3r;
  float O3r = u1r - u3i, O3i = u1i + u3r;
  vr[0] = E0r + O0r; vi[0] = E0i + O0i;
  vr[4] = E0r - O0r; vi[4] = E0i - O0i;
  float a1r = C7 * (O1r + O1i), a1i = C7 * (O1i - O1r);
  vr[1] = E1r + a1r; vi[1] = E1i + a1i;
  vr[5] = E1r - a1r; vi[5] = E1i - a1i;
  vr[2] = E2r + O2i; vi[2] = E2i - O2r;
  vr[6] = E2r - O2i; vi[6] = E2i + O2r;
  float a3r = C7 * (O3i - O3r), a3i = -C7 * (O3r + O3i);
  vr[3] = E3r + a3r; vi[3] = E3i + a3i;
  vr[7] = E3r - a3r; vi[7] = E3i - a3i;
}

__device__ __forceinline__ void twid8(float (&vr)[8], float (&vi)[8], float w1r, float w1i) {
  float w2r = w1r * w1r - w1i * w1i, w2i = 2.f * w1r * w1i;
  float w3r = w2r * w1r - w2i * w1i, w3i = w2r * w1i + w2i * w1r;
  float w4r = w2r * w2r - w2i * w2i, w4i = 2.f * w2r * w2i;
  float w5r = w3r * w2r - w3i * w2i, w5i = w3r * w2i + w3i * w2r;
  float w6r = w3r * w3r - w3i * w3i, w6i = 2.f * w3r * w3i;
  float w7r = w4r * w3r - w4i * w3i, w7i = w4r * w3i + w4i * w3r;
  float t;
  t = vr[1] * w1r - vi[1] * w1i; vi[1] = vr[1] * w1i + vi[1] * w1r; vr[1] = t;
  t = vr[2] * w2r - vi[2] * w2i; vi[2] = vr[2] * w2i + vi[2] * w2r; vr[2] = t;
  t = vr[3] * w3r - vi[3] * w3i; vi[3] = vr[3] * w3i + vi[3] * w3r; vr[3] = t;
  t = vr[4] * w4r - vi[4] * w4i; vi[4] = vr[4] * w4i + vi[4] * w4r; vr[4] = t;
  t = vr[5] * w5r - vi[5] * w5i; vi[5] = vr[5] * w5i + vi[5] * w5r; vr[5] = t;
  t = vr[6] * w6r - vi[6] * w6i; vi[6] = vr[6] * w6i + vi[6] * w6r; vr[6] = t;
  t = vr[7] * w7r - vi[7] * w7i; vi[7] = vr[7] * w7i + vi[7] * w7r; vr[7] = t;
}

// ---------------- FFT amplitude + top-5 per (b,n) ----------------
// 2048-pt complex Stockham: radix-8 x3 + radix-4, in-place float2 LDS (b64
// ops halve stage LDS instruction count), pad-every-8. Mirror unpack keeps
// all 2049 SQUARED amplitudes in registers; top-8 with one barrier per round
// and OWNER-ONLY register rescan (no spills: launch_bounds 4). sqrt deferred
// to the 8 winners. fp64 direct-DFT re-rank when adjacent amp gaps <
// 1e-3*max (fp32 rank-flip guard).
__global__ __launch_bounds__(256, 4) void k_fft_top(const float* __restrict__ base, int stride,
                                                    float* __restrict__ out) {
  __shared__ float2 X[2304];    // 18.4 KiB interleaved complex
  __shared__ float2 TW[256];    // W_2048^t
  __shared__ float RVb[2][4];
  __shared__ int   RIb[2][4];
  __shared__ double DA[NCAND];
  const int tid = threadIdx.x;
  const int bn  = blockIdx.x;   // b*N + n

  // twiddles via native sin/cos (|angle| < 0.4 rad; error ~2^-21, guarded by
  // the fp64 refine gate): W_4096^tid native, W_2048^tid by double angle.
  const float ang = -3.14159265358979323846f * (float)tid * (1.0f / 2048.0f);
  const float s4 = __sinf(ang), c4 = __cosf(ang);
  const float tb4r = c4, tb4i = s4;            // W_4096^tid
  const float cn = c4 * c4 - s4 * s4;          // cos(2*ang)
  const float sn = 2.0f * c4 * s4;             // sin(2*ang)
  TW[tid] = make_float2(cn, sn);

  // ---- load z[t] = x[2t] + i x[2t+1], t = tid + 256 r ----
  float vr[8], vi[8];
  if (stride == 1) {
    const float2* src2 = (const float2*)(base + (size_t)bn * L_);
#pragma unroll
    for (int r = 0; r < 8; ++r) {
      const float2 v = src2[tid + 256 * r];
      vr[r] = v.x; vi[r] = v.y;
    }
  } else {
    const float* src = base + (size_t)(bn >> 8) * ((size_t)L_ * N_) + (bn & (N_ - 1));
#pragma unroll
    for (int r = 0; r < 8; ++r) {
      vr[r] = src[(size_t)(2 * (tid + 256 * r)) * N_];
      vi[r] = src[(size_t)(2 * (tid + 256 * r) + 1) * N_];
    }
  }

  // ---- stage 1: s=1, tb=tid ----
  dft8(vr, vi);
  twid8(vr, vi, cn, sn);
#pragma unroll
  for (int m = 0; m < 8; ++m) X[PD(8 * tid + m)] = make_float2(vr[m], vi[m]);
  __syncthreads();   // also publishes TW

  // ---- stages 2,3: s=8,64 (read-all / sync / write-all, in place) ----
#pragma unroll
  for (int st = 0; st < 2; ++st) {
    const int s = (st == 0) ? 8 : 64;
#pragma unroll
    for (int r = 0; r < 8; ++r) {
      const float2 z = X[PD(tid + 256 * r)];
      vr[r] = z.x; vi[r] = z.y;
    }
    __syncthreads();
    const int tb = tid & ~(s - 1);
    dft8(vr, vi);
    const float2 w = TW[tb];
    twid8(vr, vi, w.x, w.y);
    const int wb = tid + 7 * tb;
#pragma unroll
    for (int m = 0; m < 8; ++m) X[PD(wb + m * s)] = make_float2(vr[m], vi[m]);
    __syncthreads();
  }

  // ---- stage 4: radix-4, s=512, no twiddle ----
  {
    float2 a[8];
#pragma unroll
    for (int h = 0; h < 2; ++h) {
      const int i = tid + 256 * h;
#pragma unroll
      for (int r = 0; r < 4; ++r) a[4 * h + r] = X[PD(i + 512 * r)];
    }
    __syncthreads();
#pragma unroll
    for (int h = 0; h < 2; ++h) {
      const int i = tid + 256 * h;
      const float x0r = a[4*h+0].x, x0i = a[4*h+0].y, x1r = a[4*h+1].x, x1i = a[4*h+1].y;
      const float x2r = a[4*h+2].x, x2i = a[4*h+2].y, x3r = a[4*h+3].x, x3i = a[4*h+3].y;
      const float t0r = x0r + x2r, t0i = x0i + x2i;
      const float t1r = x0r - x2r, t1i = x0i - x2i;
      const float t2r = x1r + x3r, t2i = x1i + x3i;
      const float t3r = x1r - x3r, t3i = x1i - x3i;
      X[PD(i)]        = make_float2(t0r + t2r, t0i + t2i);
      X[PD(i + 512)]  = make_float2(t1r + t3i, t1i - t3r);
      X[PD(i + 1024)] = make_float2(t0r - t2r, t0i - t2i);
      X[PD(i + 1536)] = make_float2(t1r - t3i, t1i + t3r);
    }
    __syncthreads();
  }

  // ---- mirror unpack, SQUARED mags in registers: slot j -> bin tid+256j
  //      (av) and bin 2048-tid-256j (am); tid0 additionally owns bin 1024 ----
  const float WAC[4] = {1.f, 0.92387953f, 0.70710678f, 0.38268343f};
  const float WAS[4] = {0.f, 0.38268343f, 0.70710678f, 0.92387953f};
  float av[4], am[4];
#pragma unroll
  for (int j = 0; j < 4; ++j) {
    const int k  = tid + 256 * j;
    const int kr = (2048 - k) & 2047;
    const float2 za = X[PD(k)];
    const float2 zb = X[PD(kr)];
    const float Er = 0.5f * (za.x + zb.x), Ei = 0.5f * (za.y - zb.y);
    const float Or = 0.5f * (za.y + zb.y), Oi = 0.5f * (zb.x - za.x);
    const float cv = WAC[j] * tb4r + WAS[j] * tb4i;   // W_4096^{256j+tid}
    const float sv = WAC[j] * tb4i - WAS[j] * tb4r;
    const float pr = cv * Or - sv * Oi, pi = cv * Oi + sv * Or;  // W*O
    const float Xr = Er + pr, Xi = Ei + pi;
    const float Mr = Er - pr, Mi = Ei - pi;
    av[j] = Xr * Xr + Xi * Xi;    // |X[k]|^2
    am[j] = Mr * Mr + Mi * Mi;    // |X[2048-k]|^2
  }
  float a1024 = -1.f;
  if (tid == 0) {
    const float2 z = X[PD(1024)];
    a1024 = z.x * z.x + z.y * z.y;
  }

  // ---- top-8 on squared mags, one barrier per round, owner-only rescan ----
  const int lane = tid & 63, wid = tid >> 6;
  float bv = -1.f; int bi = 1 << 30;
#pragma unroll
  for (int j = 0; j < 4; ++j) {
    const int k = tid + 256 * j;
    if (av[j] > bv || (av[j] == bv && k < bi)) { bv = av[j]; bi = k; }
    const int mk = 2048 - k;
    if (am[j] > bv || (am[j] == bv && mk < bi)) { bv = am[j]; bi = mk; }
  }
  if (tid == 0 && a1024 > bv) { bv = a1024; bi = 1024; }

  float tv[NCAND]; int ti[NCAND];
#pragma unroll
  for (int rr = 0; rr < NCAND; ++rr) {
    float rv = bv; int ri = bi;
#pragma unroll
    for (int off = 32; off > 0; off >>= 1) {
      const float v2 = __shfl_down(rv, off);
      const int   i2 = __shfl_down(ri, off);
      if (v2 > rv || (v2 == rv && i2 < ri)) { rv = v2; ri = i2; }
    }
    if (lane == 0) { RVb[rr & 1][wid] = rv; RIb[rr & 1][wid] = ri; }
    __syncthreads();
    float mv = RVb[rr & 1][0]; int mi = RIb[rr & 1][0];
#pragma unroll
    for (int w = 1; w < 4; ++w) {
      const float v2 = RVb[rr & 1][w]; const int i2 = RIb[rr & 1][w];
      if (v2 > mv || (v2 == mv && i2 < mi)) { mv = v2; mi = i2; }
    }
    tv[rr] = mv; ti[rr] = mi;     // identical in every thread
    // mask + rescan ONLY in the owning thread (registers, no barrier)
    bool own = false;
    if (mi == 1024) {
      if (tid == 0) { a1024 = -1.f; own = true; }
    } else {
      const int d = (mi < 1024) ? mi : (2048 - mi);
      if ((d & 255) == tid) {
        own = true;
        if (mi < 1024) av[d >> 8] = -1.f; else am[d >> 8] = -1.f;
      }
    }
    if (own) {
      bv = -1.f; bi = 1 << 30;
#pragma unroll
      for (int j = 0; j < 4; ++j) {
        const int k = tid + 256 * j;
        if (av[j] > bv || (av[j] == bv && k < bi)) { bv = av[j]; bi = k; }
        const int mk = 2048 - k;
        if (am[j] > bv || (am[j] == bv && mk < bi)) { bv = am[j]; bi = mk; }
      }
      if (tid == 0 && a1024 > bv) { bv = a1024; bi = 1024; }
    }
  }

  // ---- sqrt the 8 winners; near-tie gate on amplitude gaps (uniform) ----
  float ta[NCAND];
#pragma unroll
  for (int r = 0; r < NCAND; ++r) ta[r] = sqrtf(tv[r]);
  int need = 0;
  {
    const float thr = 1e-3f * ta[0];
#pragma unroll
    for (int r = 0; r < 5; ++r) {
      if (ta[r] - ta[r + 1] < thr) need = 1;
    }
  }

  if (need) {
    // exact fp64 direct DFT of the 8 candidate bins
    const int g = tid >> 5;        // candidate 0..7
    const int j = tid & 31;        // lane in group
    int k = ti[0];
#pragma unroll
    for (int r = 1; r < NCAND; ++r) { if (g == r) k = ti[r]; }
    const int t0 = 128 * j;
    const int e0 = (int)(((long long)k * (long long)t0) & 4095LL);
    double sp, cp;  sincos(-2.0 * 3.14159265358979323846 * (double)e0 / 4096.0, &sp, &cp);
    double sw, cw;  sincos(-2.0 * 3.14159265358979323846 * (double)k  / 4096.0, &sw, &cw);
    double ar = 0.0, ai = 0.0;
    if (stride == 1) {
      const float* xr_ = base + (size_t)bn * L_ + t0;
      for (int t = 0; t < 128; ++t) {
        const double xv = (double)xr_[t];
        ar += xv * cp; ai += xv * sp;
        const double ncp = cp * cw - sp * sw;
        sp = cp * sw + sp * cw; cp = ncp;
      }
    } else {
      const float* xr_ = base + (size_t)(bn >> 8) * ((size_t)L_ * N_) + (bn & (N_ - 1));
      for (int t = 0; t < 128; ++t) {
        const double xv = (double)xr_[(size_t)(t0 + t) * N_];
        ar += xv * cp; ai += xv * sp;
        const double ncp = cp * cw - sp * sw;
        sp = cp * sw + sp * cw; cp = ncp;
      }
    }
#pragma unroll
    for (int off = 16; off > 0; off >>= 1) {   // reduce within 32-lane group
      ar += __shfl_down(ar, off, 32);
      ai += __shfl_down(ai, off, 32);
    }
    if (j == 0) DA[g] = sqrt(ar * ar + ai * ai);
    __syncthreads();
    if (tid == 0) {
      double da[NCAND]; int di[NCAND];
#pragma unroll
      for (int r = 0; r < NCAND; ++r) { da[r] = DA[r]; di[r] = ti[r]; }
      // insertion sort: value desc, index asc on ties
      for (int i2 = 1; i2 < NCAND; ++i2) {
        const double v = da[i2]; const int ii = di[i2];
        int p = i2 - 1;
        while (p >= 0 && (da[p] < v || (da[p] == v && di[p] > ii))) {
          da[p + 1] = da[p]; di[p + 1] = di[p]; --p;
        }
        da[p + 1] = v; di[p + 1] = ii;
      }
      float* op = out + (size_t)bn * 19;
      const double den = da[0] + 2e-8;
#pragma unroll
      for (int r = 0; r < 5; ++r) {
        op[4 + r] = (float)di[r] * (1.0f / (float)L_);
        op[9 + r] = (float)(da[r] / den);
      }
    }
  } else if (tid == 0) {
    float* op = out + (size_t)bn * 19;
    const float den = ta[0] + 2e-8f;    // (max + eps) + eps
#pragma unroll
    for (int r = 0; r < 5; ++r) {
      op[4 + r] = (float)ti[r] * (1.0f / (float)L_);
      op[9 + r] = ta[r] / den;
    }
  }
}

extern "C" void kernel_launch(void* const* d_in, const int* in_sizes, int n_in,
                              void* d_out, int out_size, void* d_ws, size_t ws_size,
                              hipStream_t stream) {
  const float* x = (const float*)d_in[0];
  // d_in[1..4] = depth-gate weights: provably unused (level-0 top-5 dominates
  // aggregated; sigmoid products < 1 scale strictly-smaller later levels)
  float* out = (float*)d_out;
  float* ws  = (float*)d_ws;

  const size_t xt_elems   = (size_t)B_ * N_ * L_;        // 128 MiB transposed copy
  const size_t part_elems = (size_t)NSEG * B_ * NQ * N_; // 9 MiB partials
  const bool use_xt = ws_size >= (xt_elems + part_elems) * sizeof(float);
  float* xt = ws;
  float* P  = use_xt ? (ws + xt_elems) : ws;

  k_stats_trans<<<dim3(NSEG, B_), 256, 0, stream>>>(x, P, use_xt ? xt : nullptr,
                                                    use_xt ? 1 : 0);
  k_stats_final<<<B_, 256, 0, stream>>>(x, P, out);
  if (use_xt) {
    k_fft_top<<<B_ * N_, 256, 0, stream>>>(xt, 1, out);
  } else {
    k_fft_top<<<B_ * N_, 256, 0, stream>>>(x, N_, out);
  }
}

// Round 7
// 375.599 us; speedup vs baseline: 1.1259x; 1.1259x over previous
//
#include <hip/hip_runtime.h>
#include <math.h>

#define B_    32
#define L_    4096
#define N_    256
#define NC    2048            // complex FFT length (real-packed)
#define NSEG  32
#define SEGLEN (L_ / NSEG)    // 128
#define CHUNK 32
#define NCH   (SEGLEN / CHUNK) // 4
#define NQ    9               // S1,S2,S3,S4,C1,C3,C6,C12,C24
#define NCAND 8               // fp32 candidates kept for fp64 re-rank

__device__ __forceinline__ int PD(int i) { return i + (i >> 3); }  // pad every 8 elems

// ---------------- fused stats partials + transpose ----------------
// P[((s*B + b)*NQ + q)*N + n]; xt (B,N,L) written when do_t != 0
__global__ __launch_bounds__(256, 4) void k_stats_trans(const float* __restrict__ x,
                                                        float* __restrict__ P,
                                                        float* __restrict__ xt,
                                                        int do_t) {
  __shared__ float tile[CHUNK][N_ + 1];   // +1 pad: conflict-free transpose read
  const int s = blockIdx.x;
  const int b = blockIdx.y;
  const int n = threadIdx.x;
  const int l0 = s * SEGLEN;
  const float* xp = x + (size_t)b * L_ * N_ + n;
  float* xtb = xt + (size_t)b * N_ * L_;

  float prev[CHUNK];
#pragma unroll
  for (int j = 0; j < CHUNK; ++j) {
    const int l = l0 - CHUNK + j;
    prev[j] = (l >= 0) ? xp[(size_t)l * N_] : 0.0f;  // zero-fill: missing pairs add 0
  }
  float s1 = 0.f, s2 = 0.f, s3 = 0.f, s4 = 0.f;
  float c1 = 0.f, c3 = 0.f, c6 = 0.f, c12 = 0.f, c24 = 0.f;
  for (int c = 0; c < NCH; ++c) {
    const int lb = l0 + c * CHUNK;
    float cur[CHUNK];
#pragma unroll
    for (int j = 0; j < CHUNK; ++j) cur[j] = xp[(size_t)(lb + j) * N_];
#pragma unroll
    for (int j = 0; j < CHUNK; ++j) {
      const float v = cur[j], v2 = v * v;
      s1 += v; s2 += v2; s3 += v2 * v; s4 += v2 * v2;
    }
#pragma unroll
    for (int j = 0; j < CHUNK; ++j) {
      const float v = cur[j];
      c1  += v * ((j >= 1)  ? cur[j - 1]  : prev[CHUNK + j - 1]);
      c3  += v * ((j >= 3)  ? cur[j - 3]  : prev[CHUNK + j - 3]);
      c6  += v * ((j >= 6)  ? cur[j - 6]  : prev[CHUNK + j - 6]);
      c12 += v * ((j >= 12) ? cur[j - 12] : prev[CHUNK + j - 12]);
      c24 += v * ((j >= 24) ? cur[j - 24] : prev[CHUNK + j - 24]);
    }
    if (do_t) {
#pragma unroll
      for (int j = 0; j < CHUNK; ++j) tile[j][n] = cur[j];
      __syncthreads();
#pragma unroll
      for (int it = 0; it < 8; ++it) {
        const int g  = n + 256 * it;        // [0, 2048)
        const int np = g >> 3;              // column (n') index
        const int j4 = g & 7;               // float4 within the 32-float row
        float4 w;
        w.x = tile[4 * j4 + 0][np];
        w.y = tile[4 * j4 + 1][np];
        w.z = tile[4 * j4 + 2][np];
        w.w = tile[4 * j4 + 3][np];
        *(float4*)(xtb + (size_t)np * L_ + lb + 4 * j4) = w;
      }
      __syncthreads();
    }
#pragma unroll
    for (int j = 0; j < CHUNK; ++j) prev[j] = cur[j];
  }
  float* Pp = P + (size_t)(s * B_ + b) * NQ * N_ + n;
  Pp[0 * N_] = s1; Pp[1 * N_] = s2; Pp[2 * N_] = s3; Pp[3 * N_] = s4;
  Pp[4 * N_] = c1; Pp[5 * N_] = c3; Pp[6 * N_] = c6; Pp[7 * N_] = c12; Pp[8 * N_] = c24;
}

// ---------------- stats finalize: mean/std/skew/kurt + ac[5] ----------------
__global__ __launch_bounds__(256) void k_stats_final(const float* __restrict__ x,
                                                     const float* __restrict__ P,
                                                     float* __restrict__ out) {
  const int b = blockIdx.x;
  const int n = threadIdx.x;
  float S[NQ];
#pragma unroll
  for (int q = 0; q < NQ; ++q) S[q] = 0.0f;
  for (int s = 0; s < NSEG; ++s) {
    const float* Pp = P + (size_t)(s * B_ + b) * NQ * N_ + n;
#pragma unroll
    for (int q = 0; q < NQ; ++q) S[q] += Pp[q * N_];
  }
  const float Lf = (float)L_;
  const float mu = S[0] / Lf;
  float ssd = S[1] - Lf * mu * mu;
  ssd = fmaxf(ssd, 0.0f);
  const float stdv = sqrtf(ssd / (Lf - 1.0f));     // ddof=1
  const float se  = stdv + 1e-8f;
  const float m3 = (S[2] - 3.0f * mu * S[1] + 2.0f * Lf * mu * mu * mu) / Lf;
  const float m4 = (S[3] - 4.0f * mu * S[2] + 6.0f * mu * mu * S[1]
                    - 3.0f * Lf * mu * mu * mu * mu) / Lf;
  const float se2 = se * se;
  const float skew = m3 / (se2 * se + 1e-8f);
  const float kurt = m4 / (se2 * se2 + 1e-8f) - 3.0f;

  const float* xp = x + (size_t)b * L_ * N_ + n;
  float hl[5], tl[5];
  {
    float hs = 0.0f, ts = 0.0f;
#pragma unroll
    for (int t = 0; t < 24; ++t) {
      hs += xp[(size_t)t * N_];
      ts += xp[(size_t)(L_ - 1 - t) * N_];
      if (t == 0)  { hl[0] = hs; tl[0] = ts; }
      if (t == 2)  { hl[1] = hs; tl[1] = ts; }
      if (t == 5)  { hl[2] = hs; tl[2] = ts; }
      if (t == 11) { hl[3] = hs; tl[3] = ts; }
      if (t == 23) { hl[4] = hs; tl[4] = ts; }
    }
  }
  float* op = out + ((size_t)b * N_ + n) * 19;
  op[0] = mu; op[1] = stdv; op[2] = skew; op[3] = kurt;
  const int lags[5] = {1, 3, 6, 12, 24};
  const float inv_se2 = 1.0f / se2;
#pragma unroll
  for (int i = 0; i < 5; ++i) {
    const float cnt = (float)(L_ - lags[i]);
    const float SA = S[0] - tl[i];
    const float SB = S[0] - hl[i];
    const float num = S[4 + i] - mu * (SA + SB) + cnt * mu * mu;
    op[14 + i] = num * inv_se2 / cnt;
  }
}

// ---------------- 8-point DFT in registers (forward, w8 = e^{-i pi/4}) --------
__device__ __forceinline__ void dft8(float (&vr)[8], float (&vi)[8]) {
  const float C7 = 0.70710678118654752f;
  float t0r = vr[0] + vr[4], t0i = vi[0] + vi[4];
  float t1r = vr[0] - vr[4], t1i = vi[0] - vi[4];
  float t2r = vr[2] + vr[6], t2i = vi[2] + vi[6];
  float t3r = vr[2] - vr[6], t3i = vi[2] - vi[6];
  float E0r = t0r + t2r, E0i = t0i + t2i;
  float E2r = t0r - t2r, E2i = t0i - t2i;
  float E1r = t1r + t3i, E1i = t1i - t3r;
  float E3r = t1r - t3i, E3i = t1i + t3r;
  float u0r = vr[1] + vr[5], u0i = vi[1] + vi[5];
  float u1r = vr[1] - vr[5], u1i = vi[1] - vi[5];
  float u2r = vr[3] + vr[7], u2i = vi[3] + vi[7];
  float u3r = vr[3] - vr[7], u3i = vi[3] - vi[7];
  float O0r = u0r + u2r, O0i = u0i + u2i;
  float O2r = u0r - u2r, O2i = u0i - u2i;
  float O1r = u1r + u3i, O1i = u1i - u3r;
  float O3r = u1r - u3i, O3i = u1i + u3r;
  vr[0] = E0r + O0r; vi[0] = E0i + O0i;
  vr[4] = E0r - O0r; vi[4] = E0i - O0i;
  float a1r = C7 * (O1r + O1i), a1i = C7 * (O1i - O1r);
  vr[1] = E1r + a1r; vi[1] = E1i + a1i;
  vr[5] = E1r - a1r; vi[5] = E1i - a1i;
  vr[2] = E2r + O2i; vi[2] = E2i - O2r;
  vr[6] = E2r - O2i; vi[6] = E2i + O2r;
  float a3r = C7 * (O3i - O3r), a3i = -C7 * (O3r + O3i);
  vr[3] = E3r + a3r; vi[3] = E3i + a3i;
  vr[7] = E3r - a3r; vi[7] = E3i - a3i;
}

__device__ __forceinline__ void twid8(float (&vr)[8], float (&vi)[8], float w1r, float w1i) {
  float w2r = w1r * w1r - w1i * w1i, w2i = 2.f * w1r * w1i;
  float w3r = w2r * w1r - w2i * w1i, w3i = w2r * w1i + w2i * w1r;
  float w4r = w2r * w2r - w2i * w2i, w4i = 2.f * w2r * w2i;
  float w5r = w3r * w2r - w3i * w2i, w5i = w3r * w2i + w3i * w2r;
  float w6r = w3r * w3r - w3i * w3i, w6i = 2.f * w3r * w3i;
  float w7r = w4r * w3r - w4i * w3i, w7i = w4r * w3i + w4i * w3r;
  float t;
  t = vr[1] * w1r - vi[1] * w1i; vi[1] = vr[1] * w1i + vi[1] * w1r; vr[1] = t;
  t = vr[2] * w2r - vi[2] * w2i; vi[2] = vr[2] * w2i + vi[2] * w2r; vr[2] = t;
  t = vr[3] * w3r - vi[3] * w3i; vi[3] = vr[3] * w3i + vi[3] * w3r; vr[3] = t;
  t = vr[4] * w4r - vi[4] * w4i; vi[4] = vr[4] * w4i + vi[4] * w4r; vr[4] = t;
  t = vr[5] * w5r - vi[5] * w5i; vi[5] = vr[5] * w5i + vi[5] * w5r; vr[5] = t;
  t = vr[6] * w6r - vi[6] * w6i; vi[6] = vr[6] * w6i + vi[6] * w6r; vr[6] = t;
  t = vr[7] * w7r - vi[7] * w7i; vi[7] = vr[7] * w7i + vi[7] * w7r; vr[7] = t;
}

// ---------------- FFT amplitude + top-5 per (b,n) ----------------
// 2048-pt complex Stockham: radix-8 x3 + radix-4, in-place float2 LDS (b64
// ops halve stage LDS instruction count), pad-every-8. Mirror unpack
// (X[2048-k] = conj(E - W^k O)) computes two SQUARED mags per (E,O,W); amp[]
// in LDS; top-8 uses the proven r2 structure: full 9-bin scan per round,
// tid0 merge+removal, 2 barriers/round (every "cleverer" variant regressed).
// NO dynamically-indexed private arrays (r6's 64 MB scratch lesson).
// fp64 direct-DFT re-rank when adjacent amp gaps < 1e-3*max.
__global__ __launch_bounds__(256, 4) void k_fft_top(const float* __restrict__ base, int stride,
                                                    float* __restrict__ out) {
  __shared__ float2 X[2304];    // 18.4 KiB interleaved complex
  __shared__ float2 TW[256];    // W_2048^t
  __shared__ float RV[4];
  __shared__ int   RI[4];
  __shared__ float TOPV[NCAND]; // squared mags of winners
  __shared__ int   TOPI[NCAND];
  __shared__ double DA[NCAND];
  __shared__ int REFINE;
  const int tid = threadIdx.x;
  const int bn  = blockIdx.x;   // b*N + n

  // twiddles via native sin/cos (|angle| < 0.4 rad; error ~2^-21, guarded by
  // the fp64 refine gate): W_4096^tid native, W_2048^tid by double angle.
  const float ang = -3.14159265358979323846f * (float)tid * (1.0f / 2048.0f);
  const float s4 = __sinf(ang), c4 = __cosf(ang);
  const float tb4r = c4, tb4i = s4;            // W_4096^tid
  const float cn = c4 * c4 - s4 * s4;          // cos(2*ang)
  const float sn = 2.0f * c4 * s4;             // sin(2*ang)
  TW[tid] = make_float2(cn, sn);

  // ---- load z[t] = x[2t] + i x[2t+1], t = tid + 256 r ----
  float vr[8], vi[8];
  if (stride == 1) {
    const float2* src2 = (const float2*)(base + (size_t)bn * L_);
#pragma unroll
    for (int r = 0; r < 8; ++r) {
      const float2 v = src2[tid + 256 * r];
      vr[r] = v.x; vi[r] = v.y;
    }
  } else {
    const float* src = base + (size_t)(bn >> 8) * ((size_t)L_ * N_) + (bn & (N_ - 1));
#pragma unroll
    for (int r = 0; r < 8; ++r) {
      vr[r] = src[(size_t)(2 * (tid + 256 * r)) * N_];
      vi[r] = src[(size_t)(2 * (tid + 256 * r) + 1) * N_];
    }
  }

  // ---- stage 1: s=1, tb=tid ----
  dft8(vr, vi);
  twid8(vr, vi, cn, sn);
#pragma unroll
  for (int m = 0; m < 8; ++m) X[PD(8 * tid + m)] = make_float2(vr[m], vi[m]);
  __syncthreads();   // also publishes TW

  // ---- stages 2,3: s=8,64 (read-all / sync / write-all, in place) ----
#pragma unroll
  for (int st = 0; st < 2; ++st) {
    const int s = (st == 0) ? 8 : 64;
#pragma unroll
    for (int r = 0; r < 8; ++r) {
      const float2 z = X[PD(tid + 256 * r)];
      vr[r] = z.x; vi[r] = z.y;
    }
    __syncthreads();
    const int tb = tid & ~(s - 1);
    dft8(vr, vi);
    const float2 w = TW[tb];
    twid8(vr, vi, w.x, w.y);
    const int wb = tid + 7 * tb;
#pragma unroll
    for (int m = 0; m < 8; ++m) X[PD(wb + m * s)] = make_float2(vr[m], vi[m]);
    __syncthreads();
  }

  // ---- stage 4: radix-4, s=512, no twiddle ----
  {
    float2 a[8];
#pragma unroll
    for (int h = 0; h < 2; ++h) {
      const int i = tid + 256 * h;
#pragma unroll
      for (int r = 0; r < 4; ++r) a[4 * h + r] = X[PD(i + 512 * r)];
    }
    __syncthreads();
#pragma unroll
    for (int h = 0; h < 2; ++h) {
      const int i = tid + 256 * h;
      const float x0r = a[4*h+0].x, x0i = a[4*h+0].y, x1r = a[4*h+1].x, x1i = a[4*h+1].y;
      const float x2r = a[4*h+2].x, x2i = a[4*h+2].y, x3r = a[4*h+3].x, x3i = a[4*h+3].y;
      const float t0r = x0r + x2r, t0i = x0i + x2i;
      const float t1r = x0r - x2r, t1i = x0i - x2i;
      const float t2r = x1r + x3r, t2i = x1i + x3i;
      const float t3r = x1r - x3r, t3i = x1i - x3i;
      X[PD(i)]        = make_float2(t0r + t2r, t0i + t2i);
      X[PD(i + 512)]  = make_float2(t1r + t3i, t1i - t3r);
      X[PD(i + 1024)] = make_float2(t0r - t2r, t0i - t2i);
      X[PD(i + 1536)] = make_float2(t1r - t3i, t1i + t3r);
    }
    __syncthreads();
  }

  // ---- mirror unpack (squared mags): slot j -> bins tid+256j and
  //      2048-tid-256j; tid0 additionally owns bin 1024 ----
  const float WAC[4] = {1.f, 0.92387953f, 0.70710678f, 0.38268343f};
  const float WAS[4] = {0.f, 0.38268343f, 0.70710678f, 0.92387953f};
  float av[4], am[4];
#pragma unroll
  for (int j = 0; j < 4; ++j) {
    const int k  = tid + 256 * j;
    const int kr = (2048 - k) & 2047;
    const float2 za = X[PD(k)];
    const float2 zb = X[PD(kr)];
    const float Er = 0.5f * (za.x + zb.x), Ei = 0.5f * (za.y - zb.y);
    const float Or = 0.5f * (za.y + zb.y), Oi = 0.5f * (zb.x - za.x);
    const float cv = WAC[j] * tb4r + WAS[j] * tb4i;   // W_4096^{256j+tid}
    const float sv = WAC[j] * tb4i - WAS[j] * tb4r;
    const float pr = cv * Or - sv * Oi, pi = cv * Oi + sv * Or;  // W*O
    const float Xr = Er + pr, Xi = Ei + pi;
    const float Mr = Er - pr, Mi = Ei - pi;
    av[j] = Xr * Xr + Xi * Xi;    // |X[k]|^2
    am[j] = Mr * Mr + Mi * Mi;    // |X[2048-k]|^2
  }
  float a1024 = -1.f;
  if (tid == 0) {
    const float2 z = X[PD(1024)];
    a1024 = z.x * z.x + z.y * z.y;
  }
  __syncthreads();                 // all X reads done before amp overwrites X
  float* amp = (float*)X;          // unpadded [0..2048] squared amplitudes
#pragma unroll
  for (int j = 0; j < 4; ++j) {
    amp[tid + 256 * j] = av[j];
    amp[2048 - tid - 256 * j] = am[j];
  }
  if (tid == 0) amp[1024] = a1024;
  __syncthreads();

  // ---- top-8: full LDS scan per round (r2 structure, proven fastest) ----
  const int lane = tid & 63, wid = tid >> 6;
  for (int rr = 0; rr < NCAND; ++rr) {
    float bv = -1.f; int bi = 1 << 30;
    for (int k = tid; k <= 2048; k += 256) {
      const float v = amp[k];
      if (v > bv) { bv = v; bi = k; }     // strict >: lowest index on ties
    }
#pragma unroll
    for (int off = 32; off > 0; off >>= 1) {
      const float v2 = __shfl_down(bv, off);
      const int   i2 = __shfl_down(bi, off);
      if (v2 > bv || (v2 == bv && i2 < bi)) { bv = v2; bi = i2; }
    }
    if (lane == 0) { RV[wid] = bv; RI[wid] = bi; }
    __syncthreads();
    if (tid == 0) {
      float mv = RV[0]; int mi = RI[0];
#pragma unroll
      for (int w = 1; w < 4; ++w) {
        if (RV[w] > mv || (RV[w] == mv && RI[w] < mi)) { mv = RV[w]; mi = RI[w]; }
      }
      TOPV[rr] = mv; TOPI[rr] = mi;
      amp[mi] = -1.f;                     // remove for next round
    }
    __syncthreads();
  }

  // ---- near-tie gate on amplitude (sqrt of squared winners; tid0) ----
  if (tid == 0) {
    const float ta0 = sqrtf(TOPV[0]);
    const float thr = 1e-3f * ta0;
    int need = 0;
    float prev = ta0;
#pragma unroll
    for (int r = 1; r <= 5; ++r) {
      const float cur = sqrtf(TOPV[r]);
      if (prev - cur < thr) need = 1;
      prev = cur;
    }
    REFINE = need;
  }
  __syncthreads();

  if (REFINE) {
    // exact fp64 direct DFT of the 8 candidate bins
    const int g = tid >> 5;        // candidate 0..7
    const int j = tid & 31;        // lane in group
    const int k = TOPI[g];         // LDS dynamic index: fine
    const int t0 = 128 * j;
    const int e0 = (int)(((long long)k * (long long)t0) & 4095LL);
    double sp, cp;  sincos(-2.0 * 3.14159265358979323846 * (double)e0 / 4096.0, &sp, &cp);
    double sw, cw;  sincos(-2.0 * 3.14159265358979323846 * (double)k  / 4096.0, &sw, &cw);
    double ar = 0.0, ai = 0.0;
    if (stride == 1) {
      const float* xr_ = base + (size_t)bn * L_ + t0;
      for (int t = 0; t < 128; ++t) {
        const double xv = (double)xr_[t];
        ar += xv * cp; ai += xv * sp;
        const double ncp = cp * cw - sp * sw;
        sp = cp * sw + sp * cw; cp = ncp;
      }
    } else {
      const float* xr_ = base + (size_t)(bn >> 8) * ((size_t)L_ * N_) + (bn & (N_ - 1));
      for (int t = 0; t < 128; ++t) {
        const double xv = (double)xr_[(size_t)(t0 + t) * N_];
        ar += xv * cp; ai += xv * sp;
        const double ncp = cp * cw - sp * sw;
        sp = cp * sw + sp * cw; cp = ncp;
      }
    }
#pragma unroll
    for (int off = 16; off > 0; off >>= 1) {   // reduce within 32-lane group
      ar += __shfl_down(ar, off, 32);
      ai += __shfl_down(ai, off, 32);
    }
    if (j == 0) DA[g] = sqrt(ar * ar + ai * ai);
    __syncthreads();
    if (tid == 0) {
      double da[NCAND]; int di[NCAND];
#pragma unroll
      for (int r = 0; r < NCAND; ++r) { da[r] = DA[r]; di[r] = TOPI[r]; }
      // insertion sort: value desc, index asc on ties (tid0-only, rare path)
      for (int i2 = 1; i2 < NCAND; ++i2) {
        const double v = da[i2]; const int ii = di[i2];
        int p = i2 - 1;
        while (p >= 0 && (da[p] < v || (da[p] == v && di[p] > ii))) {
          da[p + 1] = da[p]; di[p + 1] = di[p]; --p;
        }
        da[p + 1] = v; di[p + 1] = ii;
      }
      float* op = out + (size_t)bn * 19;
      const double den = da[0] + 2e-8;
#pragma unroll
      for (int r = 0; r < 5; ++r) {
        op[4 + r] = (float)di[r] * (1.0f / (float)L_);
        op[9 + r] = (float)(da[r] / den);
      }
    }
  } else if (tid == 0) {
    float* op = out + (size_t)bn * 19;
    const float ta0 = sqrtf(TOPV[0]);
    const float den = ta0 + 2e-8f;    // (max + eps) + eps
#pragma unroll
    for (int r = 0; r < 5; ++r) {
      op[4 + r] = (float)TOPI[r] * (1.0f / (float)L_);
      op[9 + r] = sqrtf(TOPV[r]) / den;
    }
  }
}

extern "C" void kernel_launch(void* const* d_in, const int* in_sizes, int n_in,
                              void* d_out, int out_size, void* d_ws, size_t ws_size,
                              hipStream_t stream) {
  const float* x = (const float*)d_in[0];
  // d_in[1..4] = depth-gate weights: provably unused (level-0 top-5 dominates
  // aggregated; sigmoid products < 1 scale strictly-smaller later levels)
  float* out = (float*)d_out;
  float* ws  = (float*)d_ws;

  const size_t xt_elems   = (size_t)B_ * N_ * L_;        // 128 MiB transposed copy
  const size_t part_elems = (size_t)NSEG * B_ * NQ * N_; // 9 MiB partials
  const bool use_xt = ws_size >= (xt_elems + part_elems) * sizeof(float);
  float* xt = ws;
  float* P  = use_xt ? (ws + xt_elems) : ws;

  k_stats_trans<<<dim3(NSEG, B_), 256, 0, stream>>>(x, P, use_xt ? xt : nullptr,
                                                    use_xt ? 1 : 0);
  k_stats_final<<<B_, 256, 0, stream>>>(x, P, out);
  if (use_xt) {
    k_fft_top<<<B_ * N_, 256, 0, stream>>>(xt, 1, out);
  } else {
    k_fft_top<<<B_ * N_, 256, 0, stream>>>(x, N_, out);
  }
}

// Round 8
// 349.345 us; speedup vs baseline: 1.2105x; 1.0752x over previous
//
#include <hip/hip_runtime.h>
#include <math.h>

#define B_    32
#define L_    4096
#define N_    256
#define NC    2048            // complex FFT length (real-packed)
#define NSEG  32
#define SEGLEN (L_ / NSEG)    // 128
#define CHUNK 32
#define NCH   (SEGLEN / CHUNK) // 4
#define NQ    9               // S1,S2,S3,S4,C1,C3,C6,C12,C24
#define NCAND 8               // fp32 candidates kept for fp64 re-rank

__device__ __forceinline__ int PD(int i) { return i + (i >> 3); }  // pad every 8 floats

// ---------------- fused stats partials + transpose ----------------
// P[((s*B + b)*NQ + q)*N + n]; xt (B,N,L) written when do_t != 0
__global__ __launch_bounds__(256, 4) void k_stats_trans(const float* __restrict__ x,
                                                        float* __restrict__ P,
                                                        float* __restrict__ xt,
                                                        int do_t) {
  __shared__ float tile[CHUNK][N_ + 1];   // +1 pad: conflict-free transpose read
  const int s = blockIdx.x;
  const int b = blockIdx.y;
  const int n = threadIdx.x;
  const int l0 = s * SEGLEN;
  const float* xp = x + (size_t)b * L_ * N_ + n;
  float* xtb = xt + (size_t)b * N_ * L_;

  float prev[CHUNK];
#pragma unroll
  for (int j = 0; j < CHUNK; ++j) {
    const int l = l0 - CHUNK + j;
    prev[j] = (l >= 0) ? xp[(size_t)l * N_] : 0.0f;  // zero-fill: missing pairs add 0
  }
  float s1 = 0.f, s2 = 0.f, s3 = 0.f, s4 = 0.f;
  float c1 = 0.f, c3 = 0.f, c6 = 0.f, c12 = 0.f, c24 = 0.f;
  for (int c = 0; c < NCH; ++c) {
    const int lb = l0 + c * CHUNK;
    float cur[CHUNK];
#pragma unroll
    for (int j = 0; j < CHUNK; ++j) cur[j] = xp[(size_t)(lb + j) * N_];
#pragma unroll
    for (int j = 0; j < CHUNK; ++j) {
      const float v = cur[j], v2 = v * v;
      s1 += v; s2 += v2; s3 += v2 * v; s4 += v2 * v2;
    }
#pragma unroll
    for (int j = 0; j < CHUNK; ++j) {
      const float v = cur[j];
      c1  += v * ((j >= 1)  ? cur[j - 1]  : prev[CHUNK + j - 1]);
      c3  += v * ((j >= 3)  ? cur[j - 3]  : prev[CHUNK + j - 3]);
      c6  += v * ((j >= 6)  ? cur[j - 6]  : prev[CHUNK + j - 6]);
      c12 += v * ((j >= 12) ? cur[j - 12] : prev[CHUNK + j - 12]);
      c24 += v * ((j >= 24) ? cur[j - 24] : prev[CHUNK + j - 24]);
    }
    if (do_t) {
#pragma unroll
      for (int j = 0; j < CHUNK; ++j) tile[j][n] = cur[j];
      __syncthreads();
#pragma unroll
      for (int it = 0; it < 8; ++it) {
        const int g  = n + 256 * it;        // [0, 2048)
        const int np = g >> 3;              // column (n') index
        const int j4 = g & 7;               // float4 within the 32-float row
        float4 w;
        w.x = tile[4 * j4 + 0][np];
        w.y = tile[4 * j4 + 1][np];
        w.z = tile[4 * j4 + 2][np];
        w.w = tile[4 * j4 + 3][np];
        *(float4*)(xtb + (size_t)np * L_ + lb + 4 * j4) = w;
      }
      __syncthreads();
    }
#pragma unroll
    for (int j = 0; j < CHUNK; ++j) prev[j] = cur[j];
  }
  float* Pp = P + (size_t)(s * B_ + b) * NQ * N_ + n;
  Pp[0 * N_] = s1; Pp[1 * N_] = s2; Pp[2 * N_] = s3; Pp[3 * N_] = s4;
  Pp[4 * N_] = c1; Pp[5 * N_] = c3; Pp[6 * N_] = c6; Pp[7 * N_] = c12; Pp[8 * N_] = c24;
}

// ---------------- stats finalize: mean/std/skew/kurt + ac[5] ----------------
__global__ __launch_bounds__(256) void k_stats_final(const float* __restrict__ x,
                                                     const float* __restrict__ P,
                                                     float* __restrict__ out) {
  const int b = blockIdx.x;
  const int n = threadIdx.x;
  float S[NQ];
#pragma unroll
  for (int q = 0; q < NQ; ++q) S[q] = 0.0f;
  for (int s = 0; s < NSEG; ++s) {
    const float* Pp = P + (size_t)(s * B_ + b) * NQ * N_ + n;
#pragma unroll
    for (int q = 0; q < NQ; ++q) S[q] += Pp[q * N_];
  }
  const float Lf = (float)L_;
  const float mu = S[0] / Lf;
  float ssd = S[1] - Lf * mu * mu;
  ssd = fmaxf(ssd, 0.0f);
  const float stdv = sqrtf(ssd / (Lf - 1.0f));     // ddof=1
  const float se  = stdv + 1e-8f;
  const float m3 = (S[2] - 3.0f * mu * S[1] + 2.0f * Lf * mu * mu * mu) / Lf;
  const float m4 = (S[3] - 4.0f * mu * S[2] + 6.0f * mu * mu * S[1]
                    - 3.0f * Lf * mu * mu * mu * mu) / Lf;
  const float se2 = se * se;
  const float skew = m3 / (se2 * se + 1e-8f);
  const float kurt = m4 / (se2 * se2 + 1e-8f) - 3.0f;

  const float* xp = x + (size_t)b * L_ * N_ + n;
  float hl[5], tl[5];
  {
    float hs = 0.0f, ts = 0.0f;
#pragma unroll
    for (int t = 0; t < 24; ++t) {
      hs += xp[(size_t)t * N_];
      ts += xp[(size_t)(L_ - 1 - t) * N_];
      if (t == 0)  { hl[0] = hs; tl[0] = ts; }
      if (t == 2)  { hl[1] = hs; tl[1] = ts; }
      if (t == 5)  { hl[2] = hs; tl[2] = ts; }
      if (t == 11) { hl[3] = hs; tl[3] = ts; }
      if (t == 23) { hl[4] = hs; tl[4] = ts; }
    }
  }
  float* op = out + ((size_t)b * N_ + n) * 19;
  op[0] = mu; op[1] = stdv; op[2] = skew; op[3] = kurt;
  const int lags[5] = {1, 3, 6, 12, 24};
  const float inv_se2 = 1.0f / se2;
#pragma unroll
  for (int i = 0; i < 5; ++i) {
    const float cnt = (float)(L_ - lags[i]);
    const float SA = S[0] - tl[i];
    const float SB = S[0] - hl[i];
    const float num = S[4 + i] - mu * (SA + SB) + cnt * mu * mu;
    op[14 + i] = num * inv_se2 / cnt;
  }
}

// ---------------- 8-point DFT in registers (forward, w8 = e^{-i pi/4}) --------
__device__ __forceinline__ void dft8(float (&vr)[8], float (&vi)[8]) {
  const float C7 = 0.70710678118654752f;
  float t0r = vr[0] + vr[4], t0i = vi[0] + vi[4];
  float t1r = vr[0] - vr[4], t1i = vi[0] - vi[4];
  float t2r = vr[2] + vr[6], t2i = vi[2] + vi[6];
  float t3r = vr[2] - vr[6], t3i = vi[2] - vi[6];
  float E0r = t0r + t2r, E0i = t0i + t2i;
  float E2r = t0r - t2r, E2i = t0i - t2i;
  float E1r = t1r + t3i, E1i = t1i - t3r;
  float E3r = t1r - t3i, E3i = t1i + t3r;
  float u0r = vr[1] + vr[5], u0i = vi[1] + vi[5];
  float u1r = vr[1] - vr[5], u1i = vi[1] - vi[5];
  float u2r = vr[3] + vr[7], u2i = vi[3] + vi[7];
  float u3r = vr[3] - vr[7], u3i = vi[3] - vi[7];
  float O0r = u0r + u2r, O0i = u0i + u2i;
  float O2r = u0r - u2r, O2i = u0i - u2i;
  float O1r = u1r + u3i, O1i = u1i - u3r;
  float O3r = u1r - u3i, O3i = u1i + u3r;
  vr[0] = E0r + O0r; vi[0] = E0i + O0i;
  vr[4] = E0r - O0r; vi[4] = E0i - O0i;
  float a1r = C7 * (O1r + O1i), a1i = C7 * (O1i - O1r);
  vr[1] = E1r + a1r; vi[1] = E1i + a1i;
  vr[5] = E1r - a1r; vi[5] = E1i - a1i;
  vr[2] = E2r + O2i; vi[2] = E2i - O2r;
  vr[6] = E2r - O2i; vi[6] = E2i + O2r;
  float a3r = C7 * (O3i - O3r), a3i = -C7 * (O3r + O3i);
  vr[3] = E3r + a3r; vi[3] = E3i + a3i;
  vr[7] = E3r - a3r; vi[7] = E3i - a3i;
}

__device__ __forceinline__ void twid8(float (&vr)[8], float (&vi)[8], float w1r, float w1i) {
  float w2r = w1r * w1r - w1i * w1i, w2i = 2.f * w1r * w1i;
  float w3r = w2r * w1r - w2i * w1i, w3i = w2r * w1i + w2i * w1r;
  float w4r = w2r * w2r - w2i * w2i, w4i = 2.f * w2r * w2i;
  float w5r = w3r * w2r - w3i * w2i, w5i = w3r * w2i + w3i * w2r;
  float w6r = w3r * w3r - w3i * w3i, w6i = 2.f * w3r * w3i;
  float w7r = w4r * w3r - w4i * w3i, w7i = w4r * w3i + w4i * w3r;
  float t;
  t = vr[1] * w1r - vi[1] * w1i; vi[1] = vr[1] * w1i + vi[1] * w1r; vr[1] = t;
  t = vr[2] * w2r - vi[2] * w2i; vi[2] = vr[2] * w2i + vi[2] * w2r; vr[2] = t;
  t = vr[3] * w3r - vi[3] * w3i; vi[3] = vr[3] * w3i + vi[3] * w3r; vr[3] = t;
  t = vr[4] * w4r - vi[4] * w4i; vi[4] = vr[4] * w4i + vi[4] * w4r; vr[4] = t;
  t = vr[5] * w5r - vi[5] * w5i; vi[5] = vr[5] * w5i + vi[5] * w5r; vr[5] = t;
  t = vr[6] * w6r - vi[6] * w6i; vi[6] = vr[6] * w6i + vi[6] * w6r; vr[6] = t;
  t = vr[7] * w7r - vi[7] * w7i; vi[7] = vr[7] * w7i + vi[7] * w7r; vr[7] = t;
}

// ---------------- FFT amplitude + top-5 per (b,n) ----------------
// EXACTLY the proven r3 structure (130 us: radix-8 x3 + radix-4, b32 XR/XI,
// sincosf, full-scan top-8, fp64 refine gate) with ONE change: the W_2048
// twiddle tables are gone — stage twiddles come from in-wave __shfl of the
// per-thread W_2048^tid registers (tb = tid&~7 is in-wave; tid&~63 is lane 0).
// LDS drops 20992 -> ~18.6 KiB, crossing the 20480 B line: 8 blocks/CU.
__global__ __launch_bounds__(256, 4) void k_fft_top(const float* __restrict__ base, int stride,
                                                    float* __restrict__ out) {
  __shared__ float XR[2304];
  __shared__ float XI[2304];
  __shared__ float RV[4];
  __shared__ int   RI[4];
  __shared__ float TOPV[NCAND];
  __shared__ int   TOPI[NCAND];
  __shared__ double DA[NCAND];
  __shared__ int REFINE;
  const int tid = threadIdx.x;
  const int bn  = blockIdx.x;   // b*N + n

  float sn, cn;
  sincosf(-6.283185307179586f * (float)tid / 2048.0f, &sn, &cn);   // W_2048^tid
  float tb4r, tb4i;   // W_4096^tid, kept in regs for the unpack
  {
    float s4, c4;
    sincosf(-6.283185307179586f * (float)tid / 4096.0f, &s4, &c4);
    tb4r = c4; tb4i = s4;
  }

  // ---- load z[t] = x[2t] + i x[2t+1], t = tid + 256 r ----
  float vr[8], vi[8];
  if (stride == 1) {
    const float2* src2 = (const float2*)(base + (size_t)bn * L_);
#pragma unroll
    for (int r = 0; r < 8; ++r) {
      const float2 v = src2[tid + 256 * r];
      vr[r] = v.x; vi[r] = v.y;
    }
  } else {
    const float* src = base + (size_t)(bn >> 8) * ((size_t)L_ * N_) + (bn & (N_ - 1));
#pragma unroll
    for (int r = 0; r < 8; ++r) {
      vr[r] = src[(size_t)(2 * (tid + 256 * r)) * N_];
      vi[r] = src[(size_t)(2 * (tid + 256 * r) + 1) * N_];
    }
  }

  // ---- stage 1: s=1, tb=tid (twiddle from own regs) ----
  dft8(vr, vi);
  twid8(vr, vi, cn, sn);
#pragma unroll
  for (int m = 0; m < 8; ++m) {
    XR[PD(8 * tid + m)] = vr[m];
    XI[PD(8 * tid + m)] = vi[m];
  }
  __syncthreads();

  // ---- stages 2,3: s=8,64; twiddle W_2048^tb via in-wave shuffle ----
#pragma unroll
  for (int st = 0; st < 2; ++st) {
    const int s = (st == 0) ? 8 : 64;
#pragma unroll
    for (int r = 0; r < 8; ++r) {
      vr[r] = XR[PD(tid + 256 * r)];
      vi[r] = XI[PD(tid + 256 * r)];
    }
    __syncthreads();           // all reads done before any in-place write
    const int tb = tid & ~(s - 1);
    const float wr = __shfl(cn, tb & 63);   // lane tb&63 holds W_2048^tb
    const float wi = __shfl(sn, tb & 63);
    dft8(vr, vi);
    twid8(vr, vi, wr, wi);
    const int wb = tid + 7 * tb;
#pragma unroll
    for (int m = 0; m < 8; ++m) {
      XR[PD(wb + m * s)] = vr[m];
      XI[PD(wb + m * s)] = vi[m];
    }
    __syncthreads();
  }

  // ---- stage 4: radix-4, s=512, tb=0 (no twiddle), 2 butterflies/thread ----
  {
    float ar[8], ai[8];
#pragma unroll
    for (int h = 0; h < 2; ++h) {
      const int i = tid + 256 * h;
#pragma unroll
      for (int r = 0; r < 4; ++r) {
        ar[4 * h + r] = XR[PD(i + 512 * r)];
        ai[4 * h + r] = XI[PD(i + 512 * r)];
      }
    }
    __syncthreads();
#pragma unroll
    for (int h = 0; h < 2; ++h) {
      const int i = tid + 256 * h;
      const float x0r = ar[4*h+0], x0i = ai[4*h+0], x1r = ar[4*h+1], x1i = ai[4*h+1];
      const float x2r = ar[4*h+2], x2i = ai[4*h+2], x3r = ar[4*h+3], x3i = ai[4*h+3];
      const float t0r = x0r + x2r, t0i = x0i + x2i;
      const float t1r = x0r - x2r, t1i = x0i - x2i;
      const float t2r = x1r + x3r, t2i = x1i + x3i;
      const float t3r = x1r - x3r, t3i = x1i - x3i;
      XR[PD(i)]        = t0r + t2r;  XI[PD(i)]        = t0i + t2i;
      XR[PD(i + 512)]  = t1r + t3i;  XI[PD(i + 512)]  = t1i - t3r;
      XR[PD(i + 1024)] = t0r - t2r;  XI[PD(i + 1024)] = t0i - t2i;
      XR[PD(i + 1536)] = t1r - t3i;  XI[PD(i + 1536)] = t1i + t3r;
    }
    __syncthreads();
  }

  // ---- unpack: X[k] = E[k] + W_4096^k O[k] ----
  const float WAC[9] = {1.f, 0.92387953f, 0.70710678f, 0.38268343f, 0.f,
                        -0.38268343f, -0.70710678f, -0.92387953f, -1.f};
  const float WAS[9] = {0.f, 0.38268343f, 0.70710678f, 0.92387953f, 1.f,
                        0.92387953f, 0.70710678f, 0.38268343f, 0.f};
  float av[8];
#pragma unroll
  for (int j = 0; j < 8; ++j) {
    const int k  = tid + 256 * j;
    const int kr = (2048 - k) & 2047;
    const float zar = XR[PD(k)],  zai = XI[PD(k)];
    const float zbr = XR[PD(kr)], zbi = -XI[PD(kr)];
    const float Er = 0.5f * (zar + zbr), Ei = 0.5f * (zai + zbi);
    const float Or = 0.5f * (zai - zbi), Oi = -0.5f * (zar - zbr);
    const float cv = WAC[j] * tb4r + WAS[j] * tb4i;
    const float sv = WAC[j] * tb4i - WAS[j] * tb4r;
    const float Xr = Er + cv * Or - sv * Oi;
    const float Xi = Ei + cv * Oi + sv * Or;
    av[j] = sqrtf(Xr * Xr + Xi * Xi);
  }
  float a2048 = 0.f;
  if (tid == 0) a2048 = fabsf(XR[0] - XI[0]);   // Nyquist
  __syncthreads();
  float* amp = XR;   // unpadded [0..2048]
#pragma unroll
  for (int j = 0; j < 8; ++j) amp[tid + 256 * j] = av[j];
  if (tid == 0) amp[2048] = a2048;
  __syncthreads();

  // ---- fp32 top-8 extraction (full scan per round — proven fastest) ----
  const int lane = tid & 63, wid = tid >> 6;
  for (int rr = 0; rr < NCAND; ++rr) {
    float bv = -1.f; int bi = 1 << 30;
#pragma unroll
    for (int j = 0; j < 8; ++j) {
      const int k = tid + 256 * j;
      const float v = amp[k];
      if (v > bv) { bv = v; bi = k; }      // strict >: lowest index on ties
    }
    if (tid == 0) {
      const float v = amp[2048];
      if (v > bv) { bv = v; bi = 2048; }
    }
#pragma unroll
    for (int off = 32; off > 0; off >>= 1) {
      const float v2 = __shfl_down(bv, off);
      const int   i2 = __shfl_down(bi, off);
      if (v2 > bv || (v2 == bv && i2 < bi)) { bv = v2; bi = i2; }
    }
    if (lane == 0) { RV[wid] = bv; RI[wid] = bi; }
    __syncthreads();
    if (tid == 0) {
      float mv = RV[0]; int mi = RI[0];
#pragma unroll
      for (int w = 1; w < 4; ++w) {
        if (RV[w] > mv || (RV[w] == mv && RI[w] < mi)) { mv = RV[w]; mi = RI[w]; }
      }
      TOPV[rr] = mv; TOPI[rr] = mi;
      amp[mi] = -1.f;
    }
    __syncthreads();
  }

  // ---- near-tie gate (block-uniform) ----
  if (tid == 0) {
    int need = 0;
    const float thr = 1e-3f * TOPV[0];
#pragma unroll
    for (int r = 0; r < 5; ++r) {
      if (TOPV[r] - TOPV[r + 1] < thr) need = 1;
    }
    REFINE = need;
  }
  __syncthreads();

  if (REFINE) {
    // exact fp64 direct DFT of the 8 candidate bins
    const int g = tid >> 5;        // candidate 0..7
    const int j = tid & 31;        // lane in group
    const int k = TOPI[g];
    const int t0 = 128 * j;
    const int e0 = (int)(((long long)k * (long long)t0) & 4095LL);
    double sp, cp;  sincos(-2.0 * 3.14159265358979323846 * (double)e0 / 4096.0, &sp, &cp);
    double sw, cw;  sincos(-2.0 * 3.14159265358979323846 * (double)k  / 4096.0, &sw, &cw);
    double ar = 0.0, ai = 0.0;
    if (stride == 1) {
      const float* xr_ = base + (size_t)bn * L_ + t0;
      for (int t = 0; t < 128; ++t) {
        const double xv = (double)xr_[t];
        ar += xv * cp; ai += xv * sp;
        const double ncp = cp * cw - sp * sw;
        sp = cp * sw + sp * cw; cp = ncp;
      }
    } else {
      const float* xr_ = base + (size_t)(bn >> 8) * ((size_t)L_ * N_) + (bn & (N_ - 1));
      for (int t = 0; t < 128; ++t) {
        const double xv = (double)xr_[(size_t)(t0 + t) * N_];
        ar += xv * cp; ai += xv * sp;
        const double ncp = cp * cw - sp * sw;
        sp = cp * sw + sp * cw; cp = ncp;
      }
    }
#pragma unroll
    for (int off = 16; off > 0; off >>= 1) {   // reduce within 32-lane group
      ar += __shfl_down(ar, off, 32);
      ai += __shfl_down(ai, off, 32);
    }
    if (j == 0) DA[g] = sqrt(ar * ar + ai * ai);
    __syncthreads();
    if (tid == 0) {
      double da[NCAND]; int di[NCAND];
#pragma unroll
      for (int r = 0; r < NCAND; ++r) { da[r] = DA[r]; di[r] = TOPI[r]; }
      // insertion sort: value desc, index asc on ties
      for (int i2 = 1; i2 < NCAND; ++i2) {
        const double v = da[i2]; const int ii = di[i2];
        int p = i2 - 1;
        while (p >= 0 && (da[p] < v || (da[p] == v && di[p] > ii))) {
          da[p + 1] = da[p]; di[p + 1] = di[p]; --p;
        }
        da[p + 1] = v; di[p + 1] = ii;
      }
      float* op = out + (size_t)bn * 19;
      const double den = da[0] + 2e-8;
#pragma unroll
      for (int r = 0; r < 5; ++r) {
        op[4 + r] = (float)di[r] * (1.0f / (float)L_);
        op[9 + r] = (float)(da[r] / den);
      }
    }
  } else if (tid == 0) {
    float* op = out + (size_t)bn * 19;
    const float den = TOPV[0] + 2e-8f;    // (max + eps) + eps
#pragma unroll
    for (int r = 0; r < 5; ++r) {
      op[4 + r] = (float)TOPI[r] * (1.0f / (float)L_);
      op[9 + r] = TOPV[r] / den;
    }
  }
}

extern "C" void kernel_launch(void* const* d_in, const int* in_sizes, int n_in,
                              void* d_out, int out_size, void* d_ws, size_t ws_size,
                              hipStream_t stream) {
  const float* x = (const float*)d_in[0];
  // d_in[1..4] = depth-gate weights: provably unused (level-0 top-5 dominates
  // aggregated; sigmoid products < 1 scale strictly-smaller later levels)
  float* out = (float*)d_out;
  float* ws  = (float*)d_ws;

  const size_t xt_elems   = (size_t)B_ * N_ * L_;        // 128 MiB transposed copy
  const size_t part_elems = (size_t)NSEG * B_ * NQ * N_; // 9 MiB partials
  const bool use_xt = ws_size >= (xt_elems + part_elems) * sizeof(float);
  float* xt = ws;
  float* P  = use_xt ? (ws + xt_elems) : ws;

  k_stats_trans<<<dim3(NSEG, B_), 256, 0, stream>>>(x, P, use_xt ? xt : nullptr,
                                                    use_xt ? 1 : 0);
  k_stats_final<<<B_, 256, 0, stream>>>(x, P, out);
  if (use_xt) {
    k_fft_top<<<B_ * N_, 256, 0, stream>>>(xt, 1, out);
  } else {
    k_fft_top<<<B_ * N_, 256, 0, stream>>>(x, N_, out);
  }
}